// Round 6
// baseline (1521.748 us; speedup 1.0000x reference)
//
#include <hip/hip_runtime.h>
#include <hip/hip_bf16.h>
#include <math.h>

using bf16 = __hip_bfloat16;
typedef __attribute__((ext_vector_type(8))) short bh8;   // 8 bf16 raw (4 VGPRs)
typedef __attribute__((ext_vector_type(4))) float f4;

// ---------------- problem constants ----------------
// B=32 N=512 C=768 H=12 D=64 hid=3072, TOPK=100. ALL I/O IS FP32.
static const long long X_ELEMS = 12582912LL;   // 32*512*768

enum { EPI_F32 = 0, EPI_BIAS_RES = 2, EPI_BIAS_GELU = 3, EPI_QKV = 4, EPI_PV = 5 };

__device__ __forceinline__ float fin(float v) {
  return (fabsf(v) < 1e30f) ? v : 0.f;   // NaN/inf -> 0 (no-op on valid data)
}
__device__ __forceinline__ unsigned short f2bf(float f) {
  bf16 h = __float2bfloat16(f);
  return *reinterpret_cast<unsigned short*>(&h);
}
__device__ __forceinline__ uint4 pack8(float4 a, float4 b) {
  union { uint4 u; unsigned short h[8]; } r;
  r.h[0] = f2bf(a.x); r.h[1] = f2bf(a.y); r.h[2] = f2bf(a.z); r.h[3] = f2bf(a.w);
  r.h[4] = f2bf(b.x); r.h[5] = f2bf(b.y); r.h[6] = f2bf(b.z); r.h[7] = f2bf(b.w);
  return r.u;
}
// async global->LDS, 16B per lane; lds ptr must be wave-uniform base (HW adds lane*16)
__device__ __forceinline__ void gl_lds16(const bf16* g, unsigned short* l) {
  __builtin_amdgcn_global_load_lds((const __attribute__((address_space(1))) void*)g,
                                   (__attribute__((address_space(3))) void*)l, 16, 0, 0);
}

// ---------------- fp32 -> bf16 cast of ALL weights in one launch ----------------
__global__ __launch_bounds__(256) void cast_all(const float* __restrict__ qkv_w,
    const float* __restrict__ proj_w, const float* __restrict__ fc1_w,
    const float* __restrict__ fc2_w, bf16* __restrict__ dst) {
  int i = blockIdx.x * 256 + threadIdx.x;   // 0 .. 1769471 float4s
  const float* s; int base;
  if (i < 442368)       { s = qkv_w;  base = 0; }
  else if (i < 589824)  { s = proj_w; base = 442368; }
  else if (i < 1179648) { s = fc1_w;  base = 589824; }
  else                  { s = fc2_w;  base = 1179648; }
  float4 f = ((const float4*)s)[i - base];
  union { uint2 u; unsigned short h[4]; } r;
  r.h[0] = f2bf(f.x); r.h[1] = f2bf(f.y); r.h[2] = f2bf(f.z); r.h[3] = f2bf(f.w);
  ((uint2*)dst)[i] = r.u;
}

// ---------------- LayerNorm (row = 768), fp32 in -> bf16 out ----------------
__global__ __launch_bounds__(256) void ln_kernel(const float* __restrict__ x,
    const float* __restrict__ w, const float* __restrict__ bi, bf16* __restrict__ out) {
  int row = blockIdx.x; int t = threadIdx.x;
  const float* xr = x + (size_t)row * 768;
  float v0 = xr[t], v1 = xr[t + 256], v2 = xr[t + 512];
  float s = v0 + v1 + v2;
  float s2 = v0 * v0 + v1 * v1 + v2 * v2;
  for (int off = 32; off; off >>= 1) { s += __shfl_down(s, off); s2 += __shfl_down(s2, off); }
  __shared__ float ls[4], ls2[4];
  int wid = t >> 6, lane = t & 63;
  if (lane == 0) { ls[wid] = s; ls2[wid] = s2; }
  __syncthreads();
  float S = ls[0] + ls[1] + ls[2] + ls[3];
  float S2 = ls2[0] + ls2[1] + ls2[2] + ls2[3];
  float mean = S * (1.0f / 768.0f);
  float var = S2 * (1.0f / 768.0f) - mean * mean;
  float rstd = rsqrtf(fmaxf(var, 0.f) + 1e-5f);
  bf16* orow = out + (size_t)row * 768;
  orow[t]       = __float2bfloat16((v0 - mean) * rstd * w[t]       + bi[t]);
  orow[t + 256] = __float2bfloat16((v1 - mean) * rstd * w[t + 256] + bi[t + 256]);
  orow[t + 512] = __float2bfloat16((v2 - mean) * rstd * w[t + 512] + bi[t + 512]);
}

// ---------------- GEMM: C[M,N] = A[M,K] @ B[N,K]^T  (batched via grid.z) ----------------
// BM=128, BK=32, 256 threads = 4 waves (2x2), wave tile = 64 x (BN/2).
// bf16 A path stages via global_load_lds (dwordx4).
template<int BN, int EPI, bool AF32>
__global__ __launch_bounds__(256)
void gemm_bt(const void* __restrict__ A, const bf16* __restrict__ B, void* __restrict__ Cout,
             int M, int N, int K,
             long long sA, long long sB, long long sC,
             const float* __restrict__ bias, const float* __restrict__ resid, float alpha,
             bf16* __restrict__ qo, bf16* __restrict__ ko, bf16* __restrict__ vo) {
  const int BM = 128, BK = 32;
  const int WN = BN / 2;     // wave tile cols
  const int NB = WN / 16;    // n-blocks per wave (4 or 2)
  __shared__ unsigned short As[BM * BK];
  __shared__ unsigned short Bs[BN * BK];
  int t = threadIdx.x;
  int wid = t >> 6, lane = t & 63;
  int wm = wid >> 1, wn = wid & 1;
  int m0 = blockIdx.y * BM;
  int n0 = blockIdx.x * BN;
  int z = blockIdx.z;

  f4 acc[4][NB];
#pragma unroll
  for (int i = 0; i < 4; i++)
#pragma unroll
    for (int j = 0; j < NB; j++) acc[i][j] = f4{0.f, 0.f, 0.f, 0.f};

  int rowT = t >> 2;            // 0..63
  int colT = (t & 3) * 8;       // 0,8,16,24
  int q16 = lane >> 4;          // quad 0..3
  int r16 = lane & 15;

  unsigned short* lA = As + (size_t)wid * 512;   // wave-uniform LDS base (wid*1024 B)
  unsigned short* lB = Bs + (size_t)wid * 512;

  for (int k0 = 0; k0 < K; k0 += BK) {
    uint4 a0, a1;
    if (AF32) {
      const float* aP = (const float*)A + (long long)z * sA + (long long)(m0 + rowT) * K + (k0 + colT);
      float4 f0 = *(const float4*)aP, f1 = *(const float4*)(aP + 4);
      a0 = pack8(f0, f1);
      const float* aQ = aP + (long long)64 * K;
      f0 = *(const float4*)aQ; f1 = *(const float4*)(aQ + 4);
      a1 = pack8(f0, f1);
    }
    __syncthreads();            // previous iter's LDS readers done
    if (AF32) {
      *(uint4*)&As[rowT * BK + colT] = a0;
      *(uint4*)&As[(rowT + 64) * BK + colT] = a1;
    } else {
      const bf16* aP = (const bf16*)A + (long long)z * sA + (long long)(m0 + rowT) * K + (k0 + colT);
      gl_lds16(aP, lA);                              // rows 0..63
      gl_lds16(aP + (long long)64 * K, lA + 2048);   // rows 64..127 (+4096 B)
    }
    {
      const bf16* bP = B + (long long)z * sB + (long long)(n0 + rowT) * K + (k0 + colT);
      gl_lds16(bP, lB);
      if (BN == 128) gl_lds16(bP + (long long)64 * K, lB + 2048);
    }
    asm volatile("s_waitcnt vmcnt(0)" ::: "memory");  // async LDS writes landed
    __syncthreads();

    bh8 af[4], bfr[NB];
#pragma unroll
    for (int i = 0; i < 4; i++) {
      int r = wm * 64 + i * 16 + r16;
      af[i] = *(const bh8*)&As[r * BK + q16 * 8];
    }
#pragma unroll
    for (int j = 0; j < NB; j++) {
      int r = wn * WN + j * 16 + r16;
      bfr[j] = *(const bh8*)&Bs[r * BK + q16 * 8];
    }
#pragma unroll
    for (int i = 0; i < 4; i++)
#pragma unroll
      for (int j = 0; j < NB; j++)
        acc[i][j] = __builtin_amdgcn_mfma_f32_16x16x32_bf16(af[i], bfr[j], acc[i][j], 0, 0, 0);
  }

  long long cbase = (long long)z * sC;
#pragma unroll
  for (int i = 0; i < 4; i++) {
#pragma unroll
    for (int j = 0; j < NB; j++) {
#pragma unroll
      for (int r = 0; r < 4; r++) {
        int mg = m0 + wm * 64 + i * 16 + q16 * 4 + r;   // C row (col=lane&15, row=quad*4+reg)
        int ng = n0 + wn * WN + j * 16 + r16;           // C col
        float v = acc[i][j][r] * alpha;
        if (EPI == EPI_F32) {
          ((float*)Cout)[cbase + (long long)mg * N + ng] = fin(v);
        } else if (EPI == EPI_BIAS_RES) {               // fp32 out, fp32 bias+resid
          long long idx = cbase + (long long)mg * N + ng;
          v += bias[ng] + resid[idx];
          ((float*)Cout)[idx] = fin(v);
        } else if (EPI == EPI_BIAS_GELU) {              // exact erf, bf16 out
          v = fin(v + bias[ng]);
          float g = 0.5f * v * (1.0f + erff(v * 0.70710678118654752f));
          ((bf16*)Cout)[cbase + (long long)mg * N + ng] = __float2bfloat16(g);
        } else if (EPI == EPI_QKV) {  // scatter bf16 into q[z][n][d], k[z][n][d], vT[z][d][n]
          int b = mg >> 9, n = mg & 511;
          int which = ng / 768;
          int c = ng - which * 768;
          int h = c >> 6, d = c & 63;
          size_t zz = (size_t)(b * 12 + h);
          bf16 val = __float2bfloat16(fin(v));
          if (which == 0)      qo[zz * 32768 + n * 64 + d] = val;
          else if (which == 1) ko[zz * 32768 + n * 64 + d] = val;
          else                 vo[(zz * 64 + d) * 512 + n] = val;
        } else {  // EPI_PV: head z row mg, col ng -> AO[b*512+mg][h*64+ng] bf16
          int b = z / 12, h = z - b * 12;
          ((bf16*)Cout)[((size_t)(b * 512 + mg)) * 768 + h * 64 + ng] = __float2bfloat16(fin(v));
        }
      }
    }
  }
}

// ---------------- fused scores + exact top-100 + softmax -> probs (fp32, once) ----------------
// grid 6144 = 8 XCD x (48 z x 16 qb); 256 thr = 4 waves. Phase 1: S(32x512 fp32) via MFMA
// into 64 KB LDS (K read global->regs; K is 64KB/z, L2-resident, XCD-pinned). Phase 2:
// per-wave-per-row radix top-100 + softmax (identical logic to the proven standalone kernel),
// single fp32 probs write. Bitwise identical to the separate scores+topk path.
__global__ __launch_bounds__(256)
void attn_topk(const bf16* __restrict__ q, const bf16* __restrict__ kk,
               float* __restrict__ probs, const int* __restrict__ islast) {
  __shared__ float S[32 * 512];          // 64 KB
  int t = threadIdx.x;
  int wid = t >> 6, lane = t & 63;
  int q16 = lane >> 4, r16 = lane & 15;
  int g = blockIdx.x;
  int xcd = g & 7, idx = g >> 3;         // bijective: 6144 = 8 xcd * 48 z * 16 qb
  int z = xcd * 48 + (idx >> 4);
  int qb = idx & 15;                     // 32-row q block
  long long zoff = (long long)z * 32768;

  // wave w: q-rows qb*32 + (w>>1)*16 .. +16, kv cols (w&1)*256 .. +256
  int qrow0 = qb * 32 + (wid >> 1) * 16;
  int col0 = (wid & 1) * 256;

  // Q A-frag: row = r16, k = q16*8 + j (two K=32 halves)
  const bf16* qp = q + zoff + (long long)(qrow0 + r16) * 64 + q16 * 8;
  union { uint4 u; bh8 h; } uq0, uq1;
  uq0.u = *(const uint4*)qp;
  uq1.u = *(const uint4*)(qp + 32);

  for (int nb = 0; nb < 16; ++nb) {
    int r = col0 + nb * 16 + r16;        // kv row (B-frag row)
    const bf16* kp = kk + zoff + (long long)r * 64 + q16 * 8;
    union { uint4 u; bh8 h; } uk0, uk1;
    uk0.u = *(const uint4*)kp;
    uk1.u = *(const uint4*)(kp + 32);
    f4 a = f4{0.f, 0.f, 0.f, 0.f};
    a = __builtin_amdgcn_mfma_f32_16x16x32_bf16(uq0.h, uk0.h, a, 0, 0, 0);
    a = __builtin_amdgcn_mfma_f32_16x16x32_bf16(uq1.h, uk1.h, a, 0, 0, 0);
    int srow = (wid >> 1) * 16 + q16 * 4;     // local S row base (C: row=q16*4+rr, col=r16)
    int scol = col0 + nb * 16 + r16;
#pragma unroll
    for (int rr = 0; rr < 4; ++rr)
      S[(srow + rr) * 512 + scol] = fin(a[rr] * 0.125f);
  }
  __syncthreads();

  // phase 2: 4 waves x 8 sequential rows; R1-proven radix + softmax on LDS rows
  int isl = *islast;
  for (int rp = 0; rp < 8; ++rp) {
    int lrow = wid * 8 + rp;             // 0..31
    const float* sr = S + lrow * 512;
    float4 va = ((const float4*)sr)[lane];
    float4 vb = ((const float4*)sr)[lane + 64];
    float v[8] = {va.x, va.y, va.z, va.w, vb.x, vb.y, vb.z, vb.w};
    unsigned key[8];
    float m = -1e30f;
#pragma unroll
    for (int e = 0; e < 8; e++) {
      if (!(v[e] >= -1e38f)) v[e] = -1e38f;  // defensive clamp (no-op on valid scores)
      unsigned u = __float_as_uint(v[e]);
      key[e] = (u & 0x80000000u) ? ~u : (u | 0x80000000u);  // monotone sortable key
      m = fmaxf(m, v[e]);
    }
    for (int off = 32; off; off >>= 1) m = fmaxf(m, __shfl_xor(m, off));

    unsigned T = 0;
    if (isl == 0) {
      // exact kth-largest key via radix bisection; cnt==100 early-exit is exact
      for (int bit = 31; bit >= 0; --bit) {
        unsigned Tc = T | (1u << bit);
        int cnt = 0;
#pragma unroll
        for (int e = 0; e < 8; e++) cnt += __popcll(__ballot(key[e] >= Tc));
        if (cnt >= 100) T = Tc;
        if (cnt == 100) break;
      }
    }
    float p[8]; float Z = 0.f;
#pragma unroll
    for (int e = 0; e < 8; e++) { p[e] = (key[e] >= T) ? __expf(v[e] - m) : 0.f; Z += p[e]; }
    for (int off = 32; off; off >>= 1) Z += __shfl_xor(Z, off);
    float rz = (Z > 0.f) ? (1.0f / Z) : 0.f;
    float* og = probs + (long long)z * 262144 + (long long)(qb * 32 + lrow) * 512;
    ((float4*)og)[lane]      = float4{p[0] * rz, p[1] * rz, p[2] * rz, p[3] * rz};
    ((float4*)og)[lane + 64] = float4{p[4] * rz, p[5] * rz, p[6] * rz, p[7] * rz};
  }
}

// ---------------- launcher ----------------
extern "C" void kernel_launch(void* const* d_in, const int* in_sizes, int n_in,
                              void* d_out, int out_size, void* d_ws, size_t ws_size,
                              hipStream_t stream) {
  const float* x      = (const float*)d_in[0];
  const int*   islast = (const int*)d_in[1];
  const float* ln1_w  = (const float*)d_in[2];
  const float* ln1_b  = (const float*)d_in[3];
  const float* qkv_w  = (const float*)d_in[4];
  const float* proj_w = (const float*)d_in[5];
  const float* proj_b = (const float*)d_in[6];
  const float* ln2_w  = (const float*)d_in[7];
  const float* ln2_b  = (const float*)d_in[8];
  const float* fc1_w  = (const float*)d_in[9];
  const float* fc1_b  = (const float*)d_in[10];
  const float* fc2_w  = (const float*)d_in[11];
  const float* fc2_b  = (const float*)d_in[12];

  // ws layout, peak 89,653,248 B, phase-aliased:
  //   [0,        3538944)   wqkv  bf16
  //   [3538944,  4718592)   wproj bf16
  //   [4718592,  9437184)   wfc1  bf16
  //   [9437184,  14155776)  wfc2  bf16
  //   [14155776, 39321600)  q bf16   -> AO bf16 (after attn) -> Hbuf
  //   [39321600, 64487424)  k bf16   -> X1 f32 low half
  //   [64487424, 89653248)  vT bf16  -> X1 f32 high half
  char* ws = (char*)d_ws;
  bf16*  wqkv = (bf16*)(ws + 0LL);
  bf16*  wproj= (bf16*)(ws + 3538944LL);
  bf16*  wfc1 = (bf16*)(ws + 4718592LL);
  bf16*  wfc2 = (bf16*)(ws + 9437184LL);
  bf16*  q    = (bf16*)(ws + 14155776LL);
  bf16*  kk   = (bf16*)(ws + 39321600LL);
  bf16*  vT   = (bf16*)(ws + 64487424LL);
  bf16*  AO   = q;
  bf16*  Hbuf = q;
  float* X1   = (float*)(ws + 39321600LL);

  float* outX    = (float*)d_out;
  float* outAttn = outX + X_ELEMS;
  bf16*  XN  = (bf16*)outX;                          // LN1 out (dead after QKV gemm)
  bf16*  XN2 = (bf16*)((char*)d_out + 25165824LL);   // LN2 out (upper half of outX bytes)

  // 0. pre-cast ALL weights fp32 -> bf16
  cast_all<<<6912, 256, 0, stream>>>(qkv_w, proj_w, fc1_w, fc2_w, wqkv);
  // 1. LN1 -> XN
  ln_kernel<<<16384, 256, 0, stream>>>(x, ln1_w, ln1_b, XN);
  // 2. QKV GEMM with scatter epilogue -> q[z][n][d], k[z][n][d], vT[z][d][n]
  gemm_bt<128, EPI_QKV, false><<<dim3(18, 128, 1), 256, 0, stream>>>(
      XN, wqkv, nullptr, 16384, 2304, 768, 0, 0, 0, nullptr, nullptr, 1.0f, q, kk, vT);
  // 3. fused scores + exact top-100 + softmax; S lives in LDS, probs written ONCE.
  attn_topk<<<6144, 256, 0, stream>>>(q, kk, outAttn, islast);
  // 4. PV (A = fp32 probs, staged-converted) -> AO bf16 [B,N,C] (q slot; q dead)
  gemm_bt<64, EPI_PV, true><<<dim3(1, 4, 384), 256, 0, stream>>>(
      outAttn, vT, AO, 512, 64, 512, 262144, 32768, 0, nullptr, nullptr, 1.0f,
      nullptr, nullptr, nullptr);
  // 5. proj + bias + residual(x) -> X1 fp32 (k+vT slots; both dead)
  gemm_bt<128, EPI_BIAS_RES, false><<<dim3(6, 128, 1), 256, 0, stream>>>(
      AO, wproj, X1, 16384, 768, 768, 0, 0, 0, proj_b, x, 1.0f, nullptr, nullptr, nullptr);
  // 6. LN2 -> XN2 bf16 (outX upper bytes)
  ln_kernel<<<16384, 256, 0, stream>>>(X1, ln2_w, ln2_b, XN2);
  // 7. MLP in 4 chunks of 4096 rows: fc1+GELU -> Hbuf bf16 (q slot), fc2+resid -> outX fp32.
  //    fc2 chunk i writes outX bytes [12.58M*i, +12.58M): chunks 0-1 clobber only dead XN;
  //    chunks 2-3 clobber XN2 rows already consumed by fc1 chunks 0-1.
  for (int i = 0; i < 4; ++i) {
    const bf16* xn2c = XN2 + (long long)i * 4096 * 768;
    gemm_bt<128, EPI_BIAS_GELU, false><<<dim3(24, 32, 1), 256, 0, stream>>>(
        xn2c, wfc1, Hbuf, 4096, 3072, 768, 0, 0, 0, fc1_b, nullptr, 1.0f,
        nullptr, nullptr, nullptr);
    gemm_bt<128, EPI_BIAS_RES, false><<<dim3(6, 32, 1), 256, 0, stream>>>(
        Hbuf, wfc2, outX + (long long)i * 4096 * 768, 4096, 768, 3072, 0, 0, 0,
        fc2_b, X1 + (long long)i * 4096 * 768, 1.0f, nullptr, nullptr, nullptr);
  }
  (void)in_sizes; (void)n_in; (void)out_size; (void)ws_size;
}

// Round 7
// 1408.710 us; speedup vs baseline: 1.0802x; 1.0802x over previous
//
#include <hip/hip_runtime.h>
#include <hip/hip_bf16.h>
#include <math.h>

using bf16 = __hip_bfloat16;
typedef __attribute__((ext_vector_type(8))) short bh8;   // 8 bf16 raw (4 VGPRs)
typedef __attribute__((ext_vector_type(4))) float f4;

// ---------------- problem constants ----------------
// B=32 N=512 C=768 H=12 D=64 hid=3072, TOPK=100. ALL I/O IS FP32.
static const long long X_ELEMS = 12582912LL;   // 32*512*768

enum { EPI_F32 = 0, EPI_BIAS_RES = 2, EPI_BIAS_GELU = 3, EPI_QKV = 4, EPI_PV = 5 };

__device__ __forceinline__ float fin(float v) {
  return (fabsf(v) < 1e30f) ? v : 0.f;   // NaN/inf -> 0 (no-op on valid data)
}
__device__ __forceinline__ unsigned short f2bf(float f) {
  bf16 h = __float2bfloat16(f);
  return *reinterpret_cast<unsigned short*>(&h);
}
__device__ __forceinline__ uint4 pack8(float4 a, float4 b) {
  union { uint4 u; unsigned short h[8]; } r;
  r.h[0] = f2bf(a.x); r.h[1] = f2bf(a.y); r.h[2] = f2bf(a.z); r.h[3] = f2bf(a.w);
  r.h[4] = f2bf(b.x); r.h[5] = f2bf(b.y); r.h[6] = f2bf(b.z); r.h[7] = f2bf(b.w);
  return r.u;
}
// async global->LDS, 16B per lane; lds ptr must be wave-uniform base (HW adds lane*16)
__device__ __forceinline__ void gl_lds16(const bf16* g, unsigned short* l) {
  __builtin_amdgcn_global_load_lds((const __attribute__((address_space(1))) void*)g,
                                   (__attribute__((address_space(3))) void*)l, 16, 0, 0);
}

// ---------------- fp32 -> bf16 cast of ALL weights in one launch ----------------
__global__ __launch_bounds__(256) void cast_all(const float* __restrict__ qkv_w,
    const float* __restrict__ proj_w, const float* __restrict__ fc1_w,
    const float* __restrict__ fc2_w, bf16* __restrict__ dst) {
  int i = blockIdx.x * 256 + threadIdx.x;   // 0 .. 1769471 float4s
  const float* s; int base;
  if (i < 442368)       { s = qkv_w;  base = 0; }
  else if (i < 589824)  { s = proj_w; base = 442368; }
  else if (i < 1179648) { s = fc1_w;  base = 589824; }
  else                  { s = fc2_w;  base = 1179648; }
  float4 f = ((const float4*)s)[i - base];
  union { uint2 u; unsigned short h[4]; } r;
  r.h[0] = f2bf(f.x); r.h[1] = f2bf(f.y); r.h[2] = f2bf(f.z); r.h[3] = f2bf(f.w);
  ((uint2*)dst)[i] = r.u;
}

// ---------------- LayerNorm (row = 768), fp32 in -> bf16 out ----------------
__global__ __launch_bounds__(256) void ln_kernel(const float* __restrict__ x,
    const float* __restrict__ w, const float* __restrict__ bi, bf16* __restrict__ out) {
  int row = blockIdx.x; int t = threadIdx.x;
  const float* xr = x + (size_t)row * 768;
  float v0 = xr[t], v1 = xr[t + 256], v2 = xr[t + 512];
  float s = v0 + v1 + v2;
  float s2 = v0 * v0 + v1 * v1 + v2 * v2;
  for (int off = 32; off; off >>= 1) { s += __shfl_down(s, off); s2 += __shfl_down(s2, off); }
  __shared__ float ls[4], ls2[4];
  int wid = t >> 6, lane = t & 63;
  if (lane == 0) { ls[wid] = s; ls2[wid] = s2; }
  __syncthreads();
  float S = ls[0] + ls[1] + ls[2] + ls[3];
  float S2 = ls2[0] + ls2[1] + ls2[2] + ls2[3];
  float mean = S * (1.0f / 768.0f);
  float var = S2 * (1.0f / 768.0f) - mean * mean;
  float rstd = rsqrtf(fmaxf(var, 0.f) + 1e-5f);
  bf16* orow = out + (size_t)row * 768;
  orow[t]       = __float2bfloat16((v0 - mean) * rstd * w[t]       + bi[t]);
  orow[t + 256] = __float2bfloat16((v1 - mean) * rstd * w[t + 256] + bi[t + 256]);
  orow[t + 512] = __float2bfloat16((v2 - mean) * rstd * w[t + 512] + bi[t + 512]);
}

// ---------------- GEMM: C[M,N] = A[M,K] @ B[N,K]^T  (batched via grid.z) ----------------
// BM=128, BK=32, 256 threads = 4 waves (2x2), wave tile = 64 x (BN/2).
// bf16 A path stages via global_load_lds (dwordx4).
template<int BN, int EPI, bool AF32>
__global__ __launch_bounds__(256)
void gemm_bt(const void* __restrict__ A, const bf16* __restrict__ B, void* __restrict__ Cout,
             int M, int N, int K,
             long long sA, long long sB, long long sC,
             const float* __restrict__ bias, const float* __restrict__ resid, float alpha,
             bf16* __restrict__ qo, bf16* __restrict__ ko, bf16* __restrict__ vo) {
  const int BM = 128, BK = 32;
  const int WN = BN / 2;     // wave tile cols
  const int NB = WN / 16;    // n-blocks per wave (4 or 2)
  __shared__ unsigned short As[BM * BK];
  __shared__ unsigned short Bs[BN * BK];
  int t = threadIdx.x;
  int wid = t >> 6, lane = t & 63;
  int wm = wid >> 1, wn = wid & 1;
  int m0 = blockIdx.y * BM;
  int n0 = blockIdx.x * BN;
  int z = blockIdx.z;

  f4 acc[4][NB];
#pragma unroll
  for (int i = 0; i < 4; i++)
#pragma unroll
    for (int j = 0; j < NB; j++) acc[i][j] = f4{0.f, 0.f, 0.f, 0.f};

  int rowT = t >> 2;            // 0..63
  int colT = (t & 3) * 8;       // 0,8,16,24
  int q16 = lane >> 4;          // quad 0..3
  int r16 = lane & 15;

  unsigned short* lA = As + (size_t)wid * 512;   // wave-uniform LDS base (wid*1024 B)
  unsigned short* lB = Bs + (size_t)wid * 512;

  for (int k0 = 0; k0 < K; k0 += BK) {
    uint4 a0, a1;
    if (AF32) {
      const float* aP = (const float*)A + (long long)z * sA + (long long)(m0 + rowT) * K + (k0 + colT);
      float4 f0 = *(const float4*)aP, f1 = *(const float4*)(aP + 4);
      a0 = pack8(f0, f1);
      const float* aQ = aP + (long long)64 * K;
      f0 = *(const float4*)aQ; f1 = *(const float4*)(aQ + 4);
      a1 = pack8(f0, f1);
    }
    __syncthreads();            // previous iter's LDS readers done
    if (AF32) {
      *(uint4*)&As[rowT * BK + colT] = a0;
      *(uint4*)&As[(rowT + 64) * BK + colT] = a1;
    } else {
      const bf16* aP = (const bf16*)A + (long long)z * sA + (long long)(m0 + rowT) * K + (k0 + colT);
      gl_lds16(aP, lA);                              // rows 0..63
      gl_lds16(aP + (long long)64 * K, lA + 2048);   // rows 64..127 (+4096 B)
    }
    {
      const bf16* bP = B + (long long)z * sB + (long long)(n0 + rowT) * K + (k0 + colT);
      gl_lds16(bP, lB);
      if (BN == 128) gl_lds16(bP + (long long)64 * K, lB + 2048);
    }
    asm volatile("s_waitcnt vmcnt(0)" ::: "memory");  // async LDS writes landed
    __syncthreads();

    bh8 af[4], bfr[NB];
#pragma unroll
    for (int i = 0; i < 4; i++) {
      int r = wm * 64 + i * 16 + r16;
      af[i] = *(const bh8*)&As[r * BK + q16 * 8];
    }
#pragma unroll
    for (int j = 0; j < NB; j++) {
      int r = wn * WN + j * 16 + r16;
      bfr[j] = *(const bh8*)&Bs[r * BK + q16 * 8];
    }
#pragma unroll
    for (int i = 0; i < 4; i++)
#pragma unroll
      for (int j = 0; j < NB; j++)
        acc[i][j] = __builtin_amdgcn_mfma_f32_16x16x32_bf16(af[i], bfr[j], acc[i][j], 0, 0, 0);
  }

  long long cbase = (long long)z * sC;
#pragma unroll
  for (int i = 0; i < 4; i++) {
#pragma unroll
    for (int j = 0; j < NB; j++) {
#pragma unroll
      for (int r = 0; r < 4; r++) {
        int mg = m0 + wm * 64 + i * 16 + q16 * 4 + r;   // C row (col=lane&15, row=quad*4+reg)
        int ng = n0 + wn * WN + j * 16 + r16;           // C col
        float v = acc[i][j][r] * alpha;
        if (EPI == EPI_F32) {
          ((float*)Cout)[cbase + (long long)mg * N + ng] = fin(v);
        } else if (EPI == EPI_BIAS_RES) {               // fp32 out, fp32 bias+resid
          long long idx = cbase + (long long)mg * N + ng;
          v += bias[ng] + resid[idx];
          ((float*)Cout)[idx] = fin(v);
        } else if (EPI == EPI_BIAS_GELU) {              // exact erf, bf16 out
          v = fin(v + bias[ng]);
          float g = 0.5f * v * (1.0f + erff(v * 0.70710678118654752f));
          ((bf16*)Cout)[cbase + (long long)mg * N + ng] = __float2bfloat16(g);
        } else if (EPI == EPI_QKV) {  // scatter bf16 into q[z][n][d], k[z][n][d], vT[z][d][n]
          int b = mg >> 9, n = mg & 511;
          int which = ng / 768;
          int c = ng - which * 768;
          int h = c >> 6, d = c & 63;
          size_t zz = (size_t)(b * 12 + h);
          bf16 val = __float2bfloat16(fin(v));
          if (which == 0)      qo[zz * 32768 + n * 64 + d] = val;
          else if (which == 1) ko[zz * 32768 + n * 64 + d] = val;
          else                 vo[(zz * 64 + d) * 512 + n] = val;
        } else {  // EPI_PV: head z row mg, col ng -> AO[b*512+mg][h*64+ng] bf16
          int b = z / 12, h = z - b * 12;
          ((bf16*)Cout)[((size_t)(b * 512 + mg)) * 768 + h * 64 + ng] = __float2bfloat16(fin(v));
        }
      }
    }
  }
}

// ---------------- fused scores + exact top-100 + softmax -> probs (fp32, once) ----------------
// grid 12288 = 8 XCD x (48 z x 32 qb); 256 thr = 4 waves; 16 q-rows per block.
// Phase 1: wave w computes all 16 rows x kv-cols [w*128, +128) via MFMA into LDS S
// (row stride 516 words: 4*516*4B % 128B-banks = 16 -> 2-way conflict = free).
// Phase 2: wave w runs radix top-100 + softmax on rows [w*4, +4) (R1-proven logic),
// single fp32 probs write. LDS 33 KB -> 4 blocks/CU (~50% occupancy) vs 64 KB/22%.
__global__ __launch_bounds__(256)
void attn_topk(const bf16* __restrict__ q, const bf16* __restrict__ kk,
               float* __restrict__ probs, const int* __restrict__ islast) {
  const int SSTR = 516;                  // padded row stride (floats)
  __shared__ float S[16 * SSTR];         // 33024 B
  int t = threadIdx.x;
  int wid = t >> 6, lane = t & 63;
  int q16 = lane >> 4, r16 = lane & 15;
  int g = blockIdx.x;
  int xcd = g & 7, idx = g >> 3;         // bijective: 12288 = 8 xcd * 48 z * 32 qb
  int z = xcd * 48 + (idx >> 5);
  int qb = idx & 31;                     // 16-row q block
  long long zoff = (long long)z * 32768;

  // Q A-frag for the block's 16 rows: row = r16, k = q16*8 + j (two K=32 halves)
  const bf16* qp = q + zoff + (long long)(qb * 16 + r16) * 64 + q16 * 8;
  union { uint4 u; bh8 h; } uq0, uq1;
  uq0.u = *(const uint4*)qp;
  uq1.u = *(const uint4*)(qp + 32);

  // wave wid covers kv rows [wid*128, +128)
  for (int nb = 0; nb < 8; ++nb) {
    int r = wid * 128 + nb * 16 + r16;   // kv row (B-frag row)
    const bf16* kp = kk + zoff + (long long)r * 64 + q16 * 8;
    union { uint4 u; bh8 h; } uk0, uk1;
    uk0.u = *(const uint4*)kp;
    uk1.u = *(const uint4*)(kp + 32);
    f4 a = f4{0.f, 0.f, 0.f, 0.f};
    a = __builtin_amdgcn_mfma_f32_16x16x32_bf16(uq0.h, uk0.h, a, 0, 0, 0);
    a = __builtin_amdgcn_mfma_f32_16x16x32_bf16(uq1.h, uk1.h, a, 0, 0, 0);
    int srow = q16 * 4;                  // C: row = q16*4 + rr, col = r16
    int scol = wid * 128 + nb * 16 + r16;
#pragma unroll
    for (int rr = 0; rr < 4; ++rr)
      S[(srow + rr) * SSTR + scol] = fin(a[rr] * 0.125f);
  }
  __syncthreads();

  // phase 2: 4 waves x 4 sequential rows; R1-proven radix + softmax on LDS rows
  int isl = *islast;
  for (int rp = 0; rp < 4; ++rp) {
    int lrow = wid * 4 + rp;             // 0..15
    const float* sr = S + lrow * SSTR;
    float4 va = ((const float4*)sr)[lane];
    float4 vb = ((const float4*)sr)[lane + 64];
    float v[8] = {va.x, va.y, va.z, va.w, vb.x, vb.y, vb.z, vb.w};
    unsigned key[8];
    float m = -1e30f;
#pragma unroll
    for (int e = 0; e < 8; e++) {
      if (!(v[e] >= -1e38f)) v[e] = -1e38f;  // defensive clamp (no-op on valid scores)
      unsigned u = __float_as_uint(v[e]);
      key[e] = (u & 0x80000000u) ? ~u : (u | 0x80000000u);  // monotone sortable key
      m = fmaxf(m, v[e]);
    }
    for (int off = 32; off; off >>= 1) m = fmaxf(m, __shfl_xor(m, off));

    unsigned T = 0;
    if (isl == 0) {
      // exact kth-largest key via radix bisection; cnt==100 early-exit is exact
      for (int bit = 31; bit >= 0; --bit) {
        unsigned Tc = T | (1u << bit);
        int cnt = 0;
#pragma unroll
        for (int e = 0; e < 8; e++) cnt += __popcll(__ballot(key[e] >= Tc));
        if (cnt >= 100) T = Tc;
        if (cnt == 100) break;
      }
    }
    float p[8]; float Z = 0.f;
#pragma unroll
    for (int e = 0; e < 8; e++) { p[e] = (key[e] >= T) ? __expf(v[e] - m) : 0.f; Z += p[e]; }
    for (int off = 32; off; off >>= 1) Z += __shfl_xor(Z, off);
    float rz = (Z > 0.f) ? (1.0f / Z) : 0.f;
    float* og = probs + (long long)z * 262144 + (long long)(qb * 16 + lrow) * 512;
    ((float4*)og)[lane]      = float4{p[0] * rz, p[1] * rz, p[2] * rz, p[3] * rz};
    ((float4*)og)[lane + 64] = float4{p[4] * rz, p[5] * rz, p[6] * rz, p[7] * rz};
  }
}

// ---------------- launcher ----------------
extern "C" void kernel_launch(void* const* d_in, const int* in_sizes, int n_in,
                              void* d_out, int out_size, void* d_ws, size_t ws_size,
                              hipStream_t stream) {
  const float* x      = (const float*)d_in[0];
  const int*   islast = (const int*)d_in[1];
  const float* ln1_w  = (const float*)d_in[2];
  const float* ln1_b  = (const float*)d_in[3];
  const float* qkv_w  = (const float*)d_in[4];
  const float* proj_w = (const float*)d_in[5];
  const float* proj_b = (const float*)d_in[6];
  const float* ln2_w  = (const float*)d_in[7];
  const float* ln2_b  = (const float*)d_in[8];
  const float* fc1_w  = (const float*)d_in[9];
  const float* fc1_b  = (const float*)d_in[10];
  const float* fc2_w  = (const float*)d_in[11];
  const float* fc2_b  = (const float*)d_in[12];

  // ws layout, peak 89,653,248 B, phase-aliased:
  //   [0,        3538944)   wqkv  bf16
  //   [3538944,  4718592)   wproj bf16
  //   [4718592,  9437184)   wfc1  bf16
  //   [9437184,  14155776)  wfc2  bf16
  //   [14155776, 39321600)  q bf16   -> AO bf16 (after attn) -> Hbuf
  //   [39321600, 64487424)  k bf16   -> X1 f32 low half
  //   [64487424, 89653248)  vT bf16  -> X1 f32 high half
  char* ws = (char*)d_ws;
  bf16*  wqkv = (bf16*)(ws + 0LL);
  bf16*  wproj= (bf16*)(ws + 3538944LL);
  bf16*  wfc1 = (bf16*)(ws + 4718592LL);
  bf16*  wfc2 = (bf16*)(ws + 9437184LL);
  bf16*  q    = (bf16*)(ws + 14155776LL);
  bf16*  kk   = (bf16*)(ws + 39321600LL);
  bf16*  vT   = (bf16*)(ws + 64487424LL);
  bf16*  AO   = q;
  bf16*  Hbuf = q;
  float* X1   = (float*)(ws + 39321600LL);

  float* outX    = (float*)d_out;
  float* outAttn = outX + X_ELEMS;
  bf16*  XN  = (bf16*)outX;                          // LN1 out (dead after QKV gemm)
  bf16*  XN2 = (bf16*)((char*)d_out + 25165824LL);   // LN2 out (upper half of outX bytes)

  // 0. pre-cast ALL weights fp32 -> bf16
  cast_all<<<6912, 256, 0, stream>>>(qkv_w, proj_w, fc1_w, fc2_w, wqkv);
  // 1. LN1 -> XN
  ln_kernel<<<16384, 256, 0, stream>>>(x, ln1_w, ln1_b, XN);
  // 2. QKV GEMM with scatter epilogue -> q[z][n][d], k[z][n][d], vT[z][d][n]
  gemm_bt<128, EPI_QKV, false><<<dim3(18, 128, 1), 256, 0, stream>>>(
      XN, wqkv, nullptr, 16384, 2304, 768, 0, 0, 0, nullptr, nullptr, 1.0f, q, kk, vT);
  // 3. fused scores + exact top-100 + softmax; S lives in LDS, probs written ONCE.
  attn_topk<<<12288, 256, 0, stream>>>(q, kk, outAttn, islast);
  // 4. PV (A = fp32 probs, staged-converted) -> AO bf16 [B,N,C] (q slot; q dead)
  gemm_bt<64, EPI_PV, true><<<dim3(1, 4, 384), 256, 0, stream>>>(
      outAttn, vT, AO, 512, 64, 512, 262144, 32768, 0, nullptr, nullptr, 1.0f,
      nullptr, nullptr, nullptr);
  // 5. proj + bias + residual(x) -> X1 fp32 (k+vT slots; both dead)
  gemm_bt<128, EPI_BIAS_RES, false><<<dim3(6, 128, 1), 256, 0, stream>>>(
      AO, wproj, X1, 16384, 768, 768, 0, 0, 0, proj_b, x, 1.0f, nullptr, nullptr, nullptr);
  // 6. LN2 -> XN2 bf16 (outX upper bytes)
  ln_kernel<<<16384, 256, 0, stream>>>(X1, ln2_w, ln2_b, XN2);
  // 7. MLP in 4 chunks of 4096 rows: fc1+GELU -> Hbuf bf16 (q slot), fc2+resid -> outX fp32.
  //    fc2 chunk i writes outX bytes [12.58M*i, +12.58M): chunks 0-1 clobber only dead XN;
  //    chunks 2-3 clobber XN2 rows already consumed by fc1 chunks 0-1.
  for (int i = 0; i < 4; ++i) {
    const bf16* xn2c = XN2 + (long long)i * 4096 * 768;
    gemm_bt<128, EPI_BIAS_GELU, false><<<dim3(24, 32, 1), 256, 0, stream>>>(
        xn2c, wfc1, Hbuf, 4096, 3072, 768, 0, 0, 0, fc1_b, nullptr, 1.0f,
        nullptr, nullptr, nullptr);
    gemm_bt<128, EPI_BIAS_RES, false><<<dim3(6, 32, 1), 256, 0, stream>>>(
        Hbuf, wfc2, outX + (long long)i * 4096 * 768, 4096, 768, 3072, 0, 0, 0,
        fc2_b, X1 + (long long)i * 4096 * 768, 1.0f, nullptr, nullptr, nullptr);
  }
  (void)in_sizes; (void)n_in; (void)out_size; (void)ws_size;
}

// Round 8
// 1316.391 us; speedup vs baseline: 1.1560x; 1.0701x over previous
//
#include <hip/hip_runtime.h>
#include <hip/hip_bf16.h>
#include <math.h>

using bf16 = __hip_bfloat16;
typedef __attribute__((ext_vector_type(8))) short bh8;   // 8 bf16 raw (4 VGPRs)
typedef __attribute__((ext_vector_type(4))) float f4;

// ---------------- problem constants ----------------
// B=32 N=512 C=768 H=12 D=64 hid=3072, TOPK=100. ALL I/O IS FP32.
static const long long X_ELEMS = 12582912LL;   // 32*512*768

enum { EPI_F32 = 0, EPI_BIAS_RES = 2, EPI_BIAS_GELU = 3, EPI_QKV = 4, EPI_PV = 5 };

__device__ __forceinline__ float fin(float v) {
  return (fabsf(v) < 1e30f) ? v : 0.f;   // NaN/inf -> 0 (no-op on valid data)
}
__device__ __forceinline__ unsigned short f2bf(float f) {
  bf16 h = __float2bfloat16(f);
  return *reinterpret_cast<unsigned short*>(&h);
}
__device__ __forceinline__ uint4 pack8(float4 a, float4 b) {
  union { uint4 u; unsigned short h[8]; } r;
  r.h[0] = f2bf(a.x); r.h[1] = f2bf(a.y); r.h[2] = f2bf(a.z); r.h[3] = f2bf(a.w);
  r.h[4] = f2bf(b.x); r.h[5] = f2bf(b.y); r.h[6] = f2bf(b.z); r.h[7] = f2bf(b.w);
  return r.u;
}
// async global->LDS, 16B per lane; lds ptr must be wave-uniform base (HW adds lane*16)
__device__ __forceinline__ void gl_lds16(const bf16* g, unsigned short* l) {
  __builtin_amdgcn_global_load_lds((const __attribute__((address_space(1))) void*)g,
                                   (__attribute__((address_space(3))) void*)l, 16, 0, 0);
}

// ---------------- fp32 -> bf16 cast of ALL weights in one launch ----------------
__global__ __launch_bounds__(256) void cast_all(const float* __restrict__ qkv_w,
    const float* __restrict__ proj_w, const float* __restrict__ fc1_w,
    const float* __restrict__ fc2_w, bf16* __restrict__ dst) {
  int i = blockIdx.x * 256 + threadIdx.x;   // 0 .. 1769471 float4s
  const float* s; int base;
  if (i < 442368)       { s = qkv_w;  base = 0; }
  else if (i < 589824)  { s = proj_w; base = 442368; }
  else if (i < 1179648) { s = fc1_w;  base = 589824; }
  else                  { s = fc2_w;  base = 1179648; }
  float4 f = ((const float4*)s)[i - base];
  union { uint2 u; unsigned short h[4]; } r;
  r.h[0] = f2bf(f.x); r.h[1] = f2bf(f.y); r.h[2] = f2bf(f.z); r.h[3] = f2bf(f.w);
  ((uint2*)dst)[i] = r.u;
}

// ---------------- LayerNorm (row = 768), fp32 in -> bf16 out ----------------
__global__ __launch_bounds__(256) void ln_kernel(const float* __restrict__ x,
    const float* __restrict__ w, const float* __restrict__ bi, bf16* __restrict__ out) {
  int row = blockIdx.x; int t = threadIdx.x;
  const float* xr = x + (size_t)row * 768;
  float v0 = xr[t], v1 = xr[t + 256], v2 = xr[t + 512];
  float s = v0 + v1 + v2;
  float s2 = v0 * v0 + v1 * v1 + v2 * v2;
  for (int off = 32; off; off >>= 1) { s += __shfl_down(s, off); s2 += __shfl_down(s2, off); }
  __shared__ float ls[4], ls2[4];
  int wid = t >> 6, lane = t & 63;
  if (lane == 0) { ls[wid] = s; ls2[wid] = s2; }
  __syncthreads();
  float S = ls[0] + ls[1] + ls[2] + ls[3];
  float S2 = ls2[0] + ls2[1] + ls2[2] + ls2[3];
  float mean = S * (1.0f / 768.0f);
  float var = S2 * (1.0f / 768.0f) - mean * mean;
  float rstd = rsqrtf(fmaxf(var, 0.f) + 1e-5f);
  bf16* orow = out + (size_t)row * 768;
  orow[t]       = __float2bfloat16((v0 - mean) * rstd * w[t]       + bi[t]);
  orow[t + 256] = __float2bfloat16((v1 - mean) * rstd * w[t + 256] + bi[t + 256]);
  orow[t + 512] = __float2bfloat16((v2 - mean) * rstd * w[t + 512] + bi[t + 512]);
}

// ---------------- GEMM: C[M,N] = A[M,K] @ B[N,K]^T  (batched via grid.z) ----------------
// BM=128, BK=32, 256 threads = 4 waves (2x2), wave tile = 64 x (BN/2).
// bf16 A path stages via global_load_lds (dwordx4).
template<int BN, int EPI, bool AF32>
__global__ __launch_bounds__(256)
void gemm_bt(const void* __restrict__ A, const bf16* __restrict__ B, void* __restrict__ Cout,
             int M, int N, int K,
             long long sA, long long sB, long long sC,
             const float* __restrict__ bias, const float* __restrict__ resid, float alpha,
             bf16* __restrict__ qo, bf16* __restrict__ ko, bf16* __restrict__ vo) {
  const int BM = 128, BK = 32;
  const int WN = BN / 2;     // wave tile cols
  const int NB = WN / 16;    // n-blocks per wave (4 or 2)
  __shared__ unsigned short As[BM * BK];
  __shared__ unsigned short Bs[BN * BK];
  int t = threadIdx.x;
  int wid = t >> 6, lane = t & 63;
  int wm = wid >> 1, wn = wid & 1;
  int m0 = blockIdx.y * BM;
  int n0 = blockIdx.x * BN;
  int z = blockIdx.z;

  f4 acc[4][NB];
#pragma unroll
  for (int i = 0; i < 4; i++)
#pragma unroll
    for (int j = 0; j < NB; j++) acc[i][j] = f4{0.f, 0.f, 0.f, 0.f};

  int rowT = t >> 2;            // 0..63
  int colT = (t & 3) * 8;       // 0,8,16,24
  int q16 = lane >> 4;          // quad 0..3
  int r16 = lane & 15;

  unsigned short* lA = As + (size_t)wid * 512;   // wave-uniform LDS base (wid*1024 B)
  unsigned short* lB = Bs + (size_t)wid * 512;

  for (int k0 = 0; k0 < K; k0 += BK) {
    uint4 a0, a1;
    if (AF32) {
      const float* aP = (const float*)A + (long long)z * sA + (long long)(m0 + rowT) * K + (k0 + colT);
      float4 f0 = *(const float4*)aP, f1 = *(const float4*)(aP + 4);
      a0 = pack8(f0, f1);
      const float* aQ = aP + (long long)64 * K;
      f0 = *(const float4*)aQ; f1 = *(const float4*)(aQ + 4);
      a1 = pack8(f0, f1);
    }
    __syncthreads();            // previous iter's LDS readers done
    if (AF32) {
      *(uint4*)&As[rowT * BK + colT] = a0;
      *(uint4*)&As[(rowT + 64) * BK + colT] = a1;
    } else {
      const bf16* aP = (const bf16*)A + (long long)z * sA + (long long)(m0 + rowT) * K + (k0 + colT);
      gl_lds16(aP, lA);                              // rows 0..63
      gl_lds16(aP + (long long)64 * K, lA + 2048);   // rows 64..127 (+4096 B)
    }
    {
      const bf16* bP = B + (long long)z * sB + (long long)(n0 + rowT) * K + (k0 + colT);
      gl_lds16(bP, lB);
      if (BN == 128) gl_lds16(bP + (long long)64 * K, lB + 2048);
    }
    asm volatile("s_waitcnt vmcnt(0)" ::: "memory");  // async LDS writes landed
    __syncthreads();

    bh8 af[4], bfr[NB];
#pragma unroll
    for (int i = 0; i < 4; i++) {
      int r = wm * 64 + i * 16 + r16;
      af[i] = *(const bh8*)&As[r * BK + q16 * 8];
    }
#pragma unroll
    for (int j = 0; j < NB; j++) {
      int r = wn * WN + j * 16 + r16;
      bfr[j] = *(const bh8*)&Bs[r * BK + q16 * 8];
    }
#pragma unroll
    for (int i = 0; i < 4; i++)
#pragma unroll
      for (int j = 0; j < NB; j++)
        acc[i][j] = __builtin_amdgcn_mfma_f32_16x16x32_bf16(af[i], bfr[j], acc[i][j], 0, 0, 0);
  }

  long long cbase = (long long)z * sC;
#pragma unroll
  for (int i = 0; i < 4; i++) {
#pragma unroll
    for (int j = 0; j < NB; j++) {
#pragma unroll
      for (int r = 0; r < 4; r++) {
        int mg = m0 + wm * 64 + i * 16 + q16 * 4 + r;   // C row (col=lane&15, row=quad*4+reg)
        int ng = n0 + wn * WN + j * 16 + r16;           // C col
        float v = acc[i][j][r] * alpha;
        if (EPI == EPI_F32) {
          ((float*)Cout)[cbase + (long long)mg * N + ng] = fin(v);
        } else if (EPI == EPI_BIAS_RES) {               // fp32 out, fp32 bias+resid
          long long idx = cbase + (long long)mg * N + ng;
          v += bias[ng] + resid[idx];
          ((float*)Cout)[idx] = fin(v);
        } else if (EPI == EPI_BIAS_GELU) {              // exact erf, bf16 out
          v = fin(v + bias[ng]);
          float g = 0.5f * v * (1.0f + erff(v * 0.70710678118654752f));
          ((bf16*)Cout)[cbase + (long long)mg * N + ng] = __float2bfloat16(g);
        } else if (EPI == EPI_QKV) {  // scatter bf16 into q[z][n][d], k[z][n][d], vT[z][d][n]
          int b = mg >> 9, n = mg & 511;
          int which = ng / 768;
          int c = ng - which * 768;
          int h = c >> 6, d = c & 63;
          size_t zz = (size_t)(b * 12 + h);
          bf16 val = __float2bfloat16(fin(v));
          if (which == 0)      qo[zz * 32768 + n * 64 + d] = val;
          else if (which == 1) ko[zz * 32768 + n * 64 + d] = val;
          else                 vo[(zz * 64 + d) * 512 + n] = val;
        } else {  // EPI_PV: head z row mg, col ng -> AO[b*512+mg][h*64+ng] bf16
          int b = z / 12, h = z - b * 12;
          ((bf16*)Cout)[((size_t)(b * 512 + mg)) * 768 + h * 64 + ng] = __float2bfloat16(fin(v));
        }
      }
    }
  }
}

// ---------------- fused scores + top-100 + softmax + PV -> probs + AO ----------------
// grid 12288 = 8 XCD x (48 z x 32 qb); 256 thr = 4 waves; 16 q-rows per block.
// Phase 1: wave w computes all 16 rows x kv-cols [w*128,+128) via MFMA into LDS S
// (row stride 516 floats -> 2-way bank conflict = free). Phase 2: wave w runs the
// R1-proven radix top-100 + softmax on rows [w*4,+4); writes fp32 probs (mandatory
// output) AND packs bf16 P in place into the same S rows (per-wave-owned rows,
// per-wave in-order LDS -> no hazard). Phase 3 (PV): wave w owns d-cols [w*16,+16);
// 16 chained MFMAs over kv chunks, V rows streamed from vT (L2-resident, XCD-pinned);
// AO written directly. Bit-identical to the separate PV GEMM (same f2bf(p*rz) values,
// same kv-chunk accumulation order). LDS 33 KB -> 4 blocks/CU.
__global__ __launch_bounds__(256)
void attn_topk(const bf16* __restrict__ q, const bf16* __restrict__ kk,
               const bf16* __restrict__ vT, float* __restrict__ probs,
               bf16* __restrict__ AO, const int* __restrict__ islast) {
  const int SSTR = 516;                  // padded row stride (floats); 1032 ushorts
  __shared__ float S[16 * SSTR];         // 33024 B; rows reused as bf16 P after phase 2
  unsigned short* Pb = (unsigned short*)S;
  int t = threadIdx.x;
  int wid = t >> 6, lane = t & 63;
  int q16 = lane >> 4, r16 = lane & 15;
  int g = blockIdx.x;
  int xcd = g & 7, idx = g >> 3;         // bijective: 12288 = 8 xcd * 48 z * 32 qb
  int z = xcd * 48 + (idx >> 5);
  int qb = idx & 31;                     // 16-row q block
  long long zoff = (long long)z * 32768;

  // Q A-frag for the block's 16 rows: row = r16, k = q16*8 + j (two K=32 halves)
  const bf16* qp = q + zoff + (long long)(qb * 16 + r16) * 64 + q16 * 8;
  union { uint4 u; bh8 h; } uq0, uq1;
  uq0.u = *(const uint4*)qp;
  uq1.u = *(const uint4*)(qp + 32);

  // ---- phase 1: S = Q K^T; wave wid covers kv rows [wid*128, +128) ----
  for (int nb = 0; nb < 8; ++nb) {
    int r = wid * 128 + nb * 16 + r16;   // kv row (B-frag row)
    const bf16* kp = kk + zoff + (long long)r * 64 + q16 * 8;
    union { uint4 u; bh8 h; } uk0, uk1;
    uk0.u = *(const uint4*)kp;
    uk1.u = *(const uint4*)(kp + 32);
    f4 a = f4{0.f, 0.f, 0.f, 0.f};
    a = __builtin_amdgcn_mfma_f32_16x16x32_bf16(uq0.h, uk0.h, a, 0, 0, 0);
    a = __builtin_amdgcn_mfma_f32_16x16x32_bf16(uq1.h, uk1.h, a, 0, 0, 0);
    int srow = q16 * 4;                  // C: row = q16*4 + rr, col = r16
    int scol = wid * 128 + nb * 16 + r16;
#pragma unroll
    for (int rr = 0; rr < 4; ++rr)
      S[(srow + rr) * SSTR + scol] = fin(a[rr] * 0.125f);
  }
  __syncthreads();

  // ---- phase 2: 4 waves x 4 rows; radix top-100 + softmax; probs + in-place bf16 P ----
  int isl = *islast;
  for (int rp = 0; rp < 4; ++rp) {
    int lrow = wid * 4 + rp;             // 0..15
    const float* sr = S + lrow * SSTR;
    float4 va = ((const float4*)sr)[lane];
    float4 vb = ((const float4*)sr)[lane + 64];
    float v[8] = {va.x, va.y, va.z, va.w, vb.x, vb.y, vb.z, vb.w};
    unsigned key[8];
    float m = -1e30f;
#pragma unroll
    for (int e = 0; e < 8; e++) {
      if (!(v[e] >= -1e38f)) v[e] = -1e38f;  // defensive clamp (no-op on valid scores)
      unsigned u = __float_as_uint(v[e]);
      key[e] = (u & 0x80000000u) ? ~u : (u | 0x80000000u);  // monotone sortable key
      m = fmaxf(m, v[e]);
    }
    for (int off = 32; off; off >>= 1) m = fmaxf(m, __shfl_xor(m, off));

    unsigned T = 0;
    if (isl == 0) {
      // exact kth-largest key via radix bisection; cnt==100 early-exit is exact
      for (int bit = 31; bit >= 0; --bit) {
        unsigned Tc = T | (1u << bit);
        int cnt = 0;
#pragma unroll
        for (int e = 0; e < 8; e++) cnt += __popcll(__ballot(key[e] >= Tc));
        if (cnt >= 100) T = Tc;
        if (cnt == 100) break;
      }
    }
    float p[8]; float Z = 0.f;
#pragma unroll
    for (int e = 0; e < 8; e++) { p[e] = (key[e] >= T) ? __expf(v[e] - m) : 0.f; Z += p[e]; }
    for (int off = 32; off; off >>= 1) Z += __shfl_xor(Z, off);
    float rz = (Z > 0.f) ? (1.0f / Z) : 0.f;
    float* og = probs + (long long)z * 262144 + (long long)(qb * 16 + lrow) * 512;
    ((float4*)og)[lane]      = float4{p[0] * rz, p[1] * rz, p[2] * rz, p[3] * rz};
    ((float4*)og)[lane + 64] = float4{p[4] * rz, p[5] * rz, p[6] * rz, p[7] * rz};
    // pack bf16 P in place (row lrow: floats no longer needed by this owner wave)
    union { uint2 u; unsigned short h[4]; } pw0, pw1;
#pragma unroll
    for (int e = 0; e < 4; e++) { pw0.h[e] = f2bf(p[e] * rz); pw1.h[e] = f2bf(p[4 + e] * rz); }
    *(uint2*)&Pb[lrow * 1032 + lane * 4]       = pw0.u;   // cols 4l..4l+3
    *(uint2*)&Pb[lrow * 1032 + 256 + lane * 4] = pw1.u;   // cols 256+4l..+3
  }
  __syncthreads();

  // ---- phase 3 (PV): wave wid owns d-cols [wid*16, +16); 16 chained MFMAs ----
  int d = wid * 16 + r16;                // B-frag row = output col
  const bf16* vp = vT + zoff + (long long)d * 512 + q16 * 8;
  f4 acc2 = f4{0.f, 0.f, 0.f, 0.f};
  for (int kc = 0; kc < 16; ++kc) {
    bh8 pa = *(const bh8*)&Pb[r16 * 1032 + kc * 32 + q16 * 8];   // A: row=r16, k=q16*8+j
    union { uint4 u; bh8 h; } uv;
    uv.u = *(const uint4*)(vp + kc * 32);
    acc2 = __builtin_amdgcn_mfma_f32_16x16x32_bf16(pa, uv.h, acc2, 0, 0, 0);
  }
  int b = z / 12, h = z - b * 12;
#pragma unroll
  for (int rr = 0; rr < 4; ++rr) {
    int qrow = qb * 16 + q16 * 4 + rr;   // C: row = q16*4+rr, col = r16 (-> d)
    AO[((size_t)(b * 512 + qrow)) * 768 + h * 64 + d] = __float2bfloat16(fin(acc2[rr]));
  }
}

// ---------------- launcher ----------------
extern "C" void kernel_launch(void* const* d_in, const int* in_sizes, int n_in,
                              void* d_out, int out_size, void* d_ws, size_t ws_size,
                              hipStream_t stream) {
  const float* x      = (const float*)d_in[0];
  const int*   islast = (const int*)d_in[1];
  const float* ln1_w  = (const float*)d_in[2];
  const float* ln1_b  = (const float*)d_in[3];
  const float* qkv_w  = (const float*)d_in[4];
  const float* proj_w = (const float*)d_in[5];
  const float* proj_b = (const float*)d_in[6];
  const float* ln2_w  = (const float*)d_in[7];
  const float* ln2_b  = (const float*)d_in[8];
  const float* fc1_w  = (const float*)d_in[9];
  const float* fc1_b  = (const float*)d_in[10];
  const float* fc2_w  = (const float*)d_in[11];
  const float* fc2_b  = (const float*)d_in[12];

  // ws layout, peak 89,653,248 B, phase-aliased:
  //   [0,        3538944)   wqkv  bf16
  //   [3538944,  4718592)   wproj bf16
  //   [4718592,  9437184)   wfc1  bf16
  //   [9437184,  14155776)  wfc2  bf16
  //   [14155776, 39321600)  q bf16   -> Hbuf (after attn; q dead)
  //   [39321600, 64487424)  k bf16   -> X1 f32 low half
  //   [64487424, 89653248)  vT bf16  -> X1 f32 high half
  // d_out: outX low 25 MB hosts XN bf16 (dead after QKV) -> AO bf16 (attn output),
  //        outX high 25 MB hosts XN2 bf16; fc2 fills outX fp32 chunk by chunk.
  char* ws = (char*)d_ws;
  bf16*  wqkv = (bf16*)(ws + 0LL);
  bf16*  wproj= (bf16*)(ws + 3538944LL);
  bf16*  wfc1 = (bf16*)(ws + 4718592LL);
  bf16*  wfc2 = (bf16*)(ws + 9437184LL);
  bf16*  q    = (bf16*)(ws + 14155776LL);
  bf16*  kk   = (bf16*)(ws + 39321600LL);
  bf16*  vT   = (bf16*)(ws + 64487424LL);
  bf16*  Hbuf = q;
  float* X1   = (float*)(ws + 39321600LL);

  float* outX    = (float*)d_out;
  float* outAttn = outX + X_ELEMS;
  bf16*  XN  = (bf16*)outX;                          // LN1 out (dead after QKV gemm)
  bf16*  AO  = (bf16*)outX;                          // attn out reuses dead XN bytes
  bf16*  XN2 = (bf16*)((char*)d_out + 25165824LL);   // LN2 out (upper half of outX bytes)

  // 0. pre-cast ALL weights fp32 -> bf16
  cast_all<<<6912, 256, 0, stream>>>(qkv_w, proj_w, fc1_w, fc2_w, wqkv);
  // 1. LN1 -> XN
  ln_kernel<<<16384, 256, 0, stream>>>(x, ln1_w, ln1_b, XN);
  // 2. QKV GEMM with scatter epilogue -> q[z][n][d], k[z][n][d], vT[z][d][n]
  gemm_bt<128, EPI_QKV, false><<<dim3(18, 128, 1), 256, 0, stream>>>(
      XN, wqkv, nullptr, 16384, 2304, 768, 0, 0, 0, nullptr, nullptr, 1.0f, q, kk, vT);
  // 3. fused scores + top-100 + softmax + PV; probs written once, AO -> outX low bytes.
  attn_topk<<<12288, 256, 0, stream>>>(q, kk, vT, outAttn, AO, islast);
  // 4. proj + bias + residual(x) -> X1 fp32 (k+vT slots; attn done, both dead)
  gemm_bt<128, EPI_BIAS_RES, false><<<dim3(6, 128, 1), 256, 0, stream>>>(
      AO, wproj, X1, 16384, 768, 768, 0, 0, 0, proj_b, x, 1.0f, nullptr, nullptr, nullptr);
  // 5. LN2 -> XN2 bf16 (outX upper bytes; AO in lower bytes already consumed)
  ln_kernel<<<16384, 256, 0, stream>>>(X1, ln2_w, ln2_b, XN2);
  // 6. MLP in 4 chunks of 4096 rows: fc1+GELU -> Hbuf bf16 (q slot), fc2+resid -> outX fp32.
  //    fc2 BN=64 -> grid (12,32)=384 blocks (vs 192 at BN=128: latency-bound, <1 block/CU).
  //    fc2 chunk i writes outX bytes [12.58M*i, +12.58M): chunks 0-1 clobber dead AO/XN;
  //    chunks 2-3 clobber XN2 rows already consumed by fc1 chunks 0-2.
  for (int i = 0; i < 4; ++i) {
    const bf16* xn2c = XN2 + (long long)i * 4096 * 768;
    gemm_bt<128, EPI_BIAS_GELU, false><<<dim3(24, 32, 1), 256, 0, stream>>>(
        xn2c, wfc1, Hbuf, 4096, 3072, 768, 0, 0, 0, fc1_b, nullptr, 1.0f,
        nullptr, nullptr, nullptr);
    gemm_bt<64, EPI_BIAS_RES, false><<<dim3(12, 32, 1), 256, 0, stream>>>(
        Hbuf, wfc2, outX + (long long)i * 4096 * 768, 4096, 768, 3072, 0, 0, 0,
        fc2_b, X1 + (long long)i * 4096 * 768, 1.0f, nullptr, nullptr, nullptr);
  }
  (void)in_sizes; (void)n_in; (void)out_size; (void)ws_size;
}